// Round 1
// baseline (699.938 us; speedup 1.0000x reference)
//
#include <hip/hip_runtime.h>
#include <hip/hip_bf16.h>
#include <math.h>

#define H 512
#define S 65
#define HS (H * S)   // 33280

// ---------------------------------------------------------------------------
// y[h*S+s] = embedding[h*S+s] * x[s],  x = concat(inputs[0:64], 1.0)
// ---------------------------------------------------------------------------
__global__ void scale_embed_kernel(const float* __restrict__ inp,
                                   const float* __restrict__ emb,
                                   float* __restrict__ y) {
    int i = blockIdx.x * blockDim.x + threadIdx.x;
    if (i < HS) {
        int s = i % S;
        float x = (s == 64) ? 1.0f : inp[s];
        y[i] = emb[i] * x;
    }
}

// ---------------------------------------------------------------------------
// Batched KQV GEMM: out[m,s] = sum_h W[m,h] * y[h,s]
// blockIdx.y: 0->k (wk), 1->q (wq), 2->v (wv); blockIdx.z: head slot
// W matrix index = (layer*3 + head0 + slot)
// Outputs k/q/v each laid out [slot][m*S+s]
// ---------------------------------------------------------------------------
__global__ void kqv_gemm_kernel(const float* __restrict__ wq,
                                const float* __restrict__ wk,
                                const float* __restrict__ wv,
                                int layer, int head0,
                                const float* __restrict__ y,
                                float* __restrict__ k,
                                float* __restrict__ q,
                                float* __restrict__ v) {
    int slot = blockIdx.z;
    int head = head0 + slot;
    int mat = layer * 3 + head;

    const float* W;
    float* out;
    if (blockIdx.y == 0)      { W = wk + (size_t)mat * H * H; out = k + (size_t)slot * HS; }
    else if (blockIdx.y == 1) { W = wq + (size_t)mat * H * H; out = q + (size_t)slot * HS; }
    else                      { W = wv + (size_t)mat * H * H; out = v + (size_t)slot * HS; }

    int i = blockIdx.x * blockDim.x + threadIdx.x;
    if (i >= HS) return;
    int m = i / S;
    int s = i % S;

    const float* Wrow = W + (size_t)m * H;
    float acc = 0.0f;
#pragma unroll 8
    for (int h = 0; h < H; ++h) {
        acc = fmaf(Wrow[h], y[h * S + s], acc);
    }
    out[i] = acc;
}

// ---------------------------------------------------------------------------
// Attention core, one block (64 threads) per (row a, head):
//   Srow[b] = sum_m k[m,a]*q[m,b]            (b in [0,65))
//   p = softmax(Srow)                         (max-subtracted)
//   att[a,hh] = sum_b p[b]*v[hh,b]            (hh in [0,512))
// att output for head `slot` goes to att + slot*S*H, layout [a*H+hh]
// ---------------------------------------------------------------------------
__global__ void attn_kernel(const float* __restrict__ k,
                            const float* __restrict__ q,
                            const float* __restrict__ v,
                            float* __restrict__ att) {
    int a = blockIdx.x;       // row in [0,65)
    int slot = blockIdx.y;    // head slot
    int tid = threadIdx.x;    // 64 threads

    const float* kk = k + (size_t)slot * HS;
    const float* qq = q + (size_t)slot * HS;
    const float* vv = v + (size_t)slot * HS;
    float* ao = att + (size_t)slot * S * H;

    __shared__ float sm[S];
    __shared__ float p[S];

    // scores for row a
    for (int b = tid; b < S; b += 64) {
        float acc = 0.0f;
#pragma unroll 8
        for (int m = 0; m < H; ++m) {
            acc = fmaf(kk[m * S + a], qq[m * S + b], acc);
        }
        sm[b] = acc;
    }
    __syncthreads();

    // softmax over the 65 entries (every thread redundantly reduces; broadcast reads)
    float maxv = -INFINITY;
    for (int i = 0; i < S; ++i) maxv = fmaxf(maxv, sm[i]);
    float sum = 0.0f;
    for (int i = 0; i < S; ++i) sum += expf(sm[i] - maxv);
    float inv = 1.0f / sum;
    for (int b = tid; b < S; b += 64) {
        p[b] = expf(sm[b] - maxv) * inv;
    }
    __syncthreads();

    // att row: att[a,hh] = sum_b p[b] * v[hh,b]
    for (int hh = tid; hh < H; hh += 64) {
        float acc = 0.0f;
#pragma unroll 5
        for (int b = 0; b < S; ++b) {
            acc = fmaf(p[b], vv[hh * S + b], acc);
        }
        ao[a * H + hh] = acc;
    }
}

// ---------------------------------------------------------------------------
// y_out[h*S+s] = relu( sum_j cat[s,j] * lin[j,h] ),  cat = [attA|attB|attC]
// atts are [S,H] row-major, lin is [3H, H] row-major
// ---------------------------------------------------------------------------
__global__ void linear_relu_T_kernel(const float* __restrict__ attA,
                                     const float* __restrict__ attB,
                                     const float* __restrict__ attC,
                                     const float* __restrict__ lin,
                                     float* __restrict__ yout) {
    int i = blockIdx.x * blockDim.x + threadIdx.x;
    if (i >= HS) return;
    int h = i / S;
    int s = i % S;

    const float* rowA = attA + (size_t)s * H;
    const float* rowB = attB + (size_t)s * H;
    const float* rowC = attC + (size_t)s * H;

    float acc = 0.0f;
#pragma unroll 8
    for (int j = 0; j < H; ++j) acc = fmaf(rowA[j], lin[j * H + h], acc);
#pragma unroll 8
    for (int j = 0; j < H; ++j) acc = fmaf(rowB[j], lin[(H + j) * H + h], acc);
#pragma unroll 8
    for (int j = 0; j < H; ++j) acc = fmaf(rowC[j], lin[(2 * H + j) * H + h], acc);

    yout[i] = fmaxf(acc, 0.0f);
}

// ---------------------------------------------------------------------------
// Final fused stage (single block, 1024 threads):
//   t[j2]  = relu( sum_j cat3[64, j] * lin3[j, j2] )      j2 in [0,1024)
//   u[hh]  = tanh( sum_j2 t[j2] * lin4[j2, hh] )          hh in [0,512)
//   out[o] = sum_hh u[hh] * lin5[hh, o]                   o in [0,64)
// ---------------------------------------------------------------------------
__global__ void final_fused_kernel(const float* __restrict__ attA,
                                   const float* __restrict__ attB,
                                   const float* __restrict__ attC,
                                   const float* __restrict__ lin3,
                                   const float* __restrict__ lin4,
                                   const float* __restrict__ lin5,
                                   float* __restrict__ out) {
    __shared__ float t[2 * H];   // 1024
    __shared__ float u[H];       // 512
    int tid = threadIdx.x;

    const float* rowA = attA + (size_t)64 * H;
    const float* rowB = attB + (size_t)64 * H;
    const float* rowC = attC + (size_t)64 * H;

    // t
    float acc = 0.0f;
#pragma unroll 8
    for (int j = 0; j < H; ++j) acc = fmaf(rowA[j], lin3[(size_t)j * (2 * H) + tid], acc);
#pragma unroll 8
    for (int j = 0; j < H; ++j) acc = fmaf(rowB[j], lin3[(size_t)(H + j) * (2 * H) + tid], acc);
#pragma unroll 8
    for (int j = 0; j < H; ++j) acc = fmaf(rowC[j], lin3[(size_t)(2 * H + j) * (2 * H) + tid], acc);
    t[tid] = fmaxf(acc, 0.0f);
    __syncthreads();

    // u
    if (tid < H) {
        float acc2 = 0.0f;
#pragma unroll 8
        for (int j2 = 0; j2 < 2 * H; ++j2) acc2 = fmaf(t[j2], lin4[(size_t)j2 * H + tid], acc2);
        u[tid] = tanhf(acc2);
    }
    __syncthreads();

    // score
    if (tid < 64) {
        float acc3 = 0.0f;
#pragma unroll 8
        for (int hh = 0; hh < H; ++hh) acc3 = fmaf(u[hh], lin5[(size_t)hh * 64 + tid], acc3);
        out[tid] = acc3;
    }
}

// ---------------------------------------------------------------------------
extern "C" void kernel_launch(void* const* d_in, const int* in_sizes, int n_in,
                              void* d_out, int out_size, void* d_ws, size_t ws_size,
                              hipStream_t stream) {
    const float* inputs  = (const float*)d_in[0];   // [1,64]
    const float* emb     = (const float*)d_in[1];   // [512,65]
    const float* wq      = (const float*)d_in[2];   // [3,3,512,512]
    const float* wk      = (const float*)d_in[3];   // [3,3,512,512]
    const float* wv      = (const float*)d_in[4];   // [3,3,512,512]
    const float* linear1 = (const float*)d_in[5];   // [1536,512]
    const float* linear2 = (const float*)d_in[6];   // [1536,512]
    const float* linear3 = (const float*)d_in[7];   // [1536,1024]
    const float* linear4 = (const float*)d_in[8];   // [1024,512]
    const float* linear5 = (const float*)d_in[9];   // [512,64]
    float* out = (float*)d_out;

    // workspace layout (floats)
    float* ws   = (float*)d_ws;
    float* y    = ws;                 // 33280
    float* kbuf = y    + HS;          // 3*33280
    float* qbuf = kbuf + 3 * HS;      // 3*33280
    float* vbuf = qbuf + 3 * HS;      // 3*33280
    float* att1 = vbuf + 3 * HS;      // 3*33280 (heads 0,1,2 of layer 1)
    float* att2 = att1 + 3 * HS;      // 33280   (layer-2 head 2)
    float* att3 = att2 + HS;          // 33280   (layer-3 head 2)

    const int nb = HS / 256;          // 130 blocks exactly

    // y0 = embedding * x
    scale_embed_kernel<<<nb, 256, 0, stream>>>(inputs, emb, y);

    // ---- Layer 1: all 3 heads ----
    kqv_gemm_kernel<<<dim3(nb, 3, 3), 256, 0, stream>>>(wq, wk, wv, 0, 0, y, kbuf, qbuf, vbuf);
    attn_kernel<<<dim3(S, 3), 64, 0, stream>>>(kbuf, qbuf, vbuf, att1);
    linear_relu_T_kernel<<<nb, 256, 0, stream>>>(att1, att1 + HS, att1 + 2 * HS, linear1, y);

    // ---- Layer 2: only head 2 is consumed ----
    kqv_gemm_kernel<<<dim3(nb, 3, 1), 256, 0, stream>>>(wq, wk, wv, 1, 2, y, kbuf, qbuf, vbuf);
    attn_kernel<<<dim3(S, 1), 64, 0, stream>>>(kbuf, qbuf, vbuf, att2);
    linear_relu_T_kernel<<<nb, 256, 0, stream>>>(att1, att1 + HS, att2, linear2, y);

    // ---- Layer 3: only head 2 is consumed ----
    kqv_gemm_kernel<<<dim3(nb, 3, 1), 256, 0, stream>>>(wq, wk, wv, 2, 2, y, kbuf, qbuf, vbuf);
    attn_kernel<<<dim3(S, 1), 64, 0, stream>>>(kbuf, qbuf, vbuf, att3);

    // ---- Final: linear3 row 64 -> tanh(linear4) -> linear5 ----
    final_fused_kernel<<<1, 1024, 0, stream>>>(att1, att1 + HS, att3,
                                               linear3, linear4, linear5, out);
}

// Round 2
// 487.784 us; speedup vs baseline: 1.4349x; 1.4349x over previous
//
#include <hip/hip_runtime.h>
#include <hip/hip_bf16.h>
#include <math.h>

#define H 512
#define S 65
#define HS (H * S)   // 33280
#define KS3 24       // linear3 K-slices (1536 / 64)
#define KS4 16       // linear4 K-slices (1024 / 64)

// ---------------------------------------------------------------------------
// y[h*S+s] = embedding[h*S+s] * x[s],  x = concat(inputs[0:64], 1.0)
// ---------------------------------------------------------------------------
__global__ void scale_embed_kernel(const float* __restrict__ inp,
                                   const float* __restrict__ emb,
                                   float* __restrict__ y) {
    int i = blockIdx.x * blockDim.x + threadIdx.x;
    if (i < HS) {
        int s = i % S;
        float x = (s == 64) ? 1.0f : inp[s];
        y[i] = emb[i] * x;
    }
}

// ---------------------------------------------------------------------------
// Batched KQV GEMM: out[m,s] = sum_h W[m,h] * y[h,s]
// blockIdx.y: 0->k (wk), 1->q (wq), 2->v (wv); blockIdx.z: head slot
// ---------------------------------------------------------------------------
__global__ void kqv_gemm_kernel(const float* __restrict__ wq,
                                const float* __restrict__ wk,
                                const float* __restrict__ wv,
                                int layer, int head0,
                                const float* __restrict__ y,
                                float* __restrict__ k,
                                float* __restrict__ q,
                                float* __restrict__ v) {
    int slot = blockIdx.z;
    int head = head0 + slot;
    int mat = layer * 3 + head;

    const float* W;
    float* out;
    if (blockIdx.y == 0)      { W = wk + (size_t)mat * H * H; out = k + (size_t)slot * HS; }
    else if (blockIdx.y == 1) { W = wq + (size_t)mat * H * H; out = q + (size_t)slot * HS; }
    else                      { W = wv + (size_t)mat * H * H; out = v + (size_t)slot * HS; }

    int i = blockIdx.x * blockDim.x + threadIdx.x;
    if (i >= HS) return;
    int m = i / S;
    int s = i % S;

    const float* Wrow = W + (size_t)m * H;
    float a0 = 0.f, a1 = 0.f, a2 = 0.f, a3 = 0.f;
    for (int h = 0; h < H; h += 4) {
        a0 = fmaf(Wrow[h + 0], y[(h + 0) * S + s], a0);
        a1 = fmaf(Wrow[h + 1], y[(h + 1) * S + s], a1);
        a2 = fmaf(Wrow[h + 2], y[(h + 2) * S + s], a2);
        a3 = fmaf(Wrow[h + 3], y[(h + 3) * S + s], a3);
    }
    out[i] = (a0 + a1) + (a2 + a3);
}

// ---------------------------------------------------------------------------
// Attention core, one block (64 threads) per (row a, head)
// ---------------------------------------------------------------------------
__global__ void attn_kernel(const float* __restrict__ k,
                            const float* __restrict__ q,
                            const float* __restrict__ v,
                            float* __restrict__ att) {
    int a = blockIdx.x;
    int slot = blockIdx.y;
    int tid = threadIdx.x;   // 64

    const float* kk = k + (size_t)slot * HS;
    const float* qq = q + (size_t)slot * HS;
    const float* vv = v + (size_t)slot * HS;
    float* ao = att + (size_t)slot * S * H;

    __shared__ float sm[S];
    __shared__ float p[S];

    for (int b = tid; b < S; b += 64) {
        float a0 = 0.f, a1 = 0.f, a2 = 0.f, a3 = 0.f;
        for (int m = 0; m < H; m += 4) {
            a0 = fmaf(kk[(m + 0) * S + a], qq[(m + 0) * S + b], a0);
            a1 = fmaf(kk[(m + 1) * S + a], qq[(m + 1) * S + b], a1);
            a2 = fmaf(kk[(m + 2) * S + a], qq[(m + 2) * S + b], a2);
            a3 = fmaf(kk[(m + 3) * S + a], qq[(m + 3) * S + b], a3);
        }
        sm[b] = (a0 + a1) + (a2 + a3);
    }
    __syncthreads();

    float maxv = -INFINITY;
    for (int i = 0; i < S; ++i) maxv = fmaxf(maxv, sm[i]);
    float sum = 0.0f;
    for (int i = 0; i < S; ++i) sum += expf(sm[i] - maxv);
    float inv = 1.0f / sum;
    for (int b = tid; b < S; b += 64) {
        p[b] = expf(sm[b] - maxv) * inv;
    }
    __syncthreads();

    for (int hh = tid; hh < H; hh += 64) {
        float acc = 0.0f;
#pragma unroll 5
        for (int b = 0; b < S; ++b) {
            acc = fmaf(p[b], vv[hh * S + b], acc);
        }
        ao[a * H + hh] = acc;
    }
}

// ---------------------------------------------------------------------------
// y_out[h*S+s] = relu( sum_j cat[s,j] * lin[j,h] ),  cat = [attA|attB|attC]
// ---------------------------------------------------------------------------
__global__ void linear_relu_T_kernel(const float* __restrict__ attA,
                                     const float* __restrict__ attB,
                                     const float* __restrict__ attC,
                                     const float* __restrict__ lin,
                                     float* __restrict__ yout) {
    int i = blockIdx.x * blockDim.x + threadIdx.x;
    if (i >= HS) return;
    int h = i / S;
    int s = i % S;

    const float* rowA = attA + (size_t)s * H;
    const float* rowB = attB + (size_t)s * H;
    const float* rowC = attC + (size_t)s * H;

    float a0 = 0.f, a1 = 0.f, a2 = 0.f, a3 = 0.f;
    for (int j = 0; j < H; j += 4) {
        a0 = fmaf(rowA[j + 0], lin[(j + 0) * H + h], a0);
        a1 = fmaf(rowA[j + 1], lin[(j + 1) * H + h], a1);
        a2 = fmaf(rowA[j + 2], lin[(j + 2) * H + h], a2);
        a3 = fmaf(rowA[j + 3], lin[(j + 3) * H + h], a3);
    }
    for (int j = 0; j < H; j += 4) {
        a0 = fmaf(rowB[j + 0], lin[(H + j + 0) * H + h], a0);
        a1 = fmaf(rowB[j + 1], lin[(H + j + 1) * H + h], a1);
        a2 = fmaf(rowB[j + 2], lin[(H + j + 2) * H + h], a2);
        a3 = fmaf(rowB[j + 3], lin[(H + j + 3) * H + h], a3);
    }
    for (int j = 0; j < H; j += 4) {
        a0 = fmaf(rowC[j + 0], lin[(2 * H + j + 0) * H + h], a0);
        a1 = fmaf(rowC[j + 1], lin[(2 * H + j + 1) * H + h], a1);
        a2 = fmaf(rowC[j + 2], lin[(2 * H + j + 2) * H + h], a2);
        a3 = fmaf(rowC[j + 3], lin[(2 * H + j + 3) * H + h], a3);
    }

    yout[i] = fmaxf((a0 + a1) + (a2 + a3), 0.0f);
}

// ---------------------------------------------------------------------------
// Final stage, kernel 1: tpart[ks][j2] = partial of linear3 GEMV (row 64 only)
// grid (4, 24), block 256.  K-slice ks covers 64 of the 1536 j values.
// ---------------------------------------------------------------------------
__global__ void lin3_partial_kernel(const float* __restrict__ attA,
                                    const float* __restrict__ attB,
                                    const float* __restrict__ attC,
                                    const float* __restrict__ lin3,
                                    float* __restrict__ tpart) {
    int j2 = blockIdx.x * 256 + threadIdx.x;   // [0, 1024)
    int ks = blockIdx.y;                       // [0, 24)
    const float* row = (ks < 8) ? (attA + (size_t)64 * H)
                     : (ks < 16 ? (attB + (size_t)64 * H)
                                : (attC + (size_t)64 * H));
    int j0 = (ks & 7) * 64;      // offset within the 512-wide att row
    int jbase = ks * 64;         // offset within 1536 rows of lin3

    float a0 = 0.f, a1 = 0.f, a2 = 0.f, a3 = 0.f;
    for (int j = 0; j < 64; j += 4) {
        a0 = fmaf(row[j0 + j + 0], lin3[(size_t)(jbase + j + 0) * 1024 + j2], a0);
        a1 = fmaf(row[j0 + j + 1], lin3[(size_t)(jbase + j + 1) * 1024 + j2], a1);
        a2 = fmaf(row[j0 + j + 2], lin3[(size_t)(jbase + j + 2) * 1024 + j2], a2);
        a3 = fmaf(row[j0 + j + 3], lin3[(size_t)(jbase + j + 3) * 1024 + j2], a3);
    }
    tpart[ks * 1024 + j2] = (a0 + a1) + (a2 + a3);
}

// ---------------------------------------------------------------------------
// Final stage, kernel 2: upart[ks][hh] = partial of linear4 GEMV.
// grid (2, 16), block 256. Each block reduces+relu's its own 64-entry t-slice.
// ---------------------------------------------------------------------------
__global__ void lin4_partial_kernel(const float* __restrict__ tpart,
                                    const float* __restrict__ lin4,
                                    float* __restrict__ upart) {
    __shared__ float tl[64];
    int hh = blockIdx.x * 256 + threadIdx.x;   // [0, 512)
    int ks = blockIdx.y;                       // [0, 16)
    int j2base = ks * 64;

    if (threadIdx.x < 64) {
        int j2 = j2base + threadIdx.x;
        float s = 0.f;
#pragma unroll
        for (int p = 0; p < KS3; ++p) s += tpart[p * 1024 + j2];
        tl[threadIdx.x] = fmaxf(s, 0.f);
    }
    __syncthreads();

    float a0 = 0.f, a1 = 0.f, a2 = 0.f, a3 = 0.f;
    for (int j = 0; j < 64; j += 4) {
        a0 = fmaf(tl[j + 0], lin4[(size_t)(j2base + j + 0) * H + hh], a0);
        a1 = fmaf(tl[j + 1], lin4[(size_t)(j2base + j + 1) * H + hh], a1);
        a2 = fmaf(tl[j + 2], lin4[(size_t)(j2base + j + 2) * H + hh], a2);
        a3 = fmaf(tl[j + 3], lin4[(size_t)(j2base + j + 3) * H + hh], a3);
    }
    upart[ks * H + hh] = (a0 + a1) + (a2 + a3);
}

// ---------------------------------------------------------------------------
// Final stage, kernel 3 (single block, 512 threads):
//   u[hh] = tanh(sum_ks upart[ks][hh]);  out[o] = sum_hh u[hh]*lin5[hh,o]
// ---------------------------------------------------------------------------
__global__ void final_out_kernel(const float* __restrict__ upart,
                                 const float* __restrict__ lin5,
                                 float* __restrict__ out) {
    __shared__ float u[H];
    __shared__ float pr[8][64];
    int tid = threadIdx.x;   // 512

    {
        float s = 0.f;
#pragma unroll
        for (int p = 0; p < KS4; ++p) s += upart[p * H + tid];
        u[tid] = tanhf(s);
    }
    __syncthreads();

    int o  = tid & 63;
    int sl = tid >> 6;           // 8 slices of 64 hh each
    float acc = 0.f;
    int h0 = sl * 64;
#pragma unroll 8
    for (int j = 0; j < 64; ++j) {
        acc = fmaf(u[h0 + j], lin5[(h0 + j) * 64 + o], acc);
    }
    pr[sl][o] = acc;
    __syncthreads();

    if (tid < 64) {
        float s = 0.f;
#pragma unroll
        for (int p = 0; p < 8; ++p) s += pr[p][tid];
        out[tid] = s;
    }
}

// ---------------------------------------------------------------------------
extern "C" void kernel_launch(void* const* d_in, const int* in_sizes, int n_in,
                              void* d_out, int out_size, void* d_ws, size_t ws_size,
                              hipStream_t stream) {
    const float* inputs  = (const float*)d_in[0];
    const float* emb     = (const float*)d_in[1];
    const float* wq      = (const float*)d_in[2];
    const float* wk      = (const float*)d_in[3];
    const float* wv      = (const float*)d_in[4];
    const float* linear1 = (const float*)d_in[5];
    const float* linear2 = (const float*)d_in[6];
    const float* linear3 = (const float*)d_in[7];
    const float* linear4 = (const float*)d_in[8];
    const float* linear5 = (const float*)d_in[9];
    float* out = (float*)d_out;

    float* ws    = (float*)d_ws;
    float* y     = ws;                 // 33280
    float* kbuf  = y     + HS;         // 3*33280
    float* qbuf  = kbuf  + 3 * HS;     // 3*33280
    float* vbuf  = qbuf  + 3 * HS;     // 3*33280
    float* att1  = vbuf  + 3 * HS;     // 3*33280
    float* att2  = att1  + 3 * HS;     // 33280
    float* att3  = att2  + HS;         // 33280
    float* tpart = att3  + HS;         // 24*1024
    float* upart = tpart + KS3 * 1024; // 16*512

    const int nb = HS / 256;           // 130

    scale_embed_kernel<<<nb, 256, 0, stream>>>(inputs, emb, y);

    // ---- Layer 1: all 3 heads ----
    kqv_gemm_kernel<<<dim3(nb, 3, 3), 256, 0, stream>>>(wq, wk, wv, 0, 0, y, kbuf, qbuf, vbuf);
    attn_kernel<<<dim3(S, 3), 64, 0, stream>>>(kbuf, qbuf, vbuf, att1);
    linear_relu_T_kernel<<<nb, 256, 0, stream>>>(att1, att1 + HS, att1 + 2 * HS, linear1, y);

    // ---- Layer 2: only head 2 is consumed ----
    kqv_gemm_kernel<<<dim3(nb, 3, 1), 256, 0, stream>>>(wq, wk, wv, 1, 2, y, kbuf, qbuf, vbuf);
    attn_kernel<<<dim3(S, 1), 64, 0, stream>>>(kbuf, qbuf, vbuf, att2);
    linear_relu_T_kernel<<<nb, 256, 0, stream>>>(att1, att1 + HS, att2, linear2, y);

    // ---- Layer 3: only head 2 is consumed ----
    kqv_gemm_kernel<<<dim3(nb, 3, 1), 256, 0, stream>>>(wq, wk, wv, 2, 2, y, kbuf, qbuf, vbuf);
    attn_kernel<<<dim3(S, 1), 64, 0, stream>>>(kbuf, qbuf, vbuf, att3);

    // ---- Final stage, parallelized ----
    lin3_partial_kernel<<<dim3(4, KS3), 256, 0, stream>>>(att1, att1 + HS, att3, linear3, tpart);
    lin4_partial_kernel<<<dim3(2, KS4), 256, 0, stream>>>(tpart, linear4, upart);
    final_out_kernel<<<1, 512, 0, stream>>>(upart, linear5, out);
}

// Round 3
// 390.940 us; speedup vs baseline: 1.7904x; 1.2477x over previous
//
#include <hip/hip_runtime.h>
#include <hip/hip_bf16.h>
#include <math.h>

#define H 512
#define S 65
#define HS (H * S)   // 33280
#define KS3 24       // linear3 K-slices (1536 / 64)
#define KS4 16       // linear4 K-slices (1024 / 64)

// All activations live in T-layout: X[s][h], row-major, contiguous over h.

// ---------------------------------------------------------------------------
// yT[s*H+h] = emb[h*S+s] * x[s]
// ---------------------------------------------------------------------------
__global__ void scale_embed_kernel(const float* __restrict__ inp,
                                   const float* __restrict__ emb,
                                   float* __restrict__ yT) {
    int i = blockIdx.x * blockDim.x + threadIdx.x;
    if (i < HS) {
        int s = i / H;
        int h = i % H;
        float x = (s == 64) ? 1.0f : inp[s];
        yT[i] = emb[h * S + s] * x;
    }
}

// ---------------------------------------------------------------------------
// kT[slot][s*H+m] = sum_h W[m,h] * yT[s*H+h]   (contiguous float4 dot)
// blockIdx.y: 0->k, 1->q, 2->v; blockIdx.z: head slot
// ---------------------------------------------------------------------------
__global__ void kqv_gemm_kernel(const float* __restrict__ wq,
                                const float* __restrict__ wk,
                                const float* __restrict__ wv,
                                int layer, int head0,
                                const float* __restrict__ yT,
                                float* __restrict__ kT,
                                float* __restrict__ qT,
                                float* __restrict__ vT) {
    int slot = blockIdx.z;
    int mat = layer * 3 + head0 + slot;

    const float* W;
    float* out;
    if (blockIdx.y == 0)      { W = wk + (size_t)mat * H * H; out = kT + (size_t)slot * HS; }
    else if (blockIdx.y == 1) { W = wq + (size_t)mat * H * H; out = qT + (size_t)slot * HS; }
    else                      { W = wv + (size_t)mat * H * H; out = vT + (size_t)slot * HS; }

    int i = blockIdx.x * blockDim.x + threadIdx.x;
    if (i >= HS) return;
    int s = i / H;    // whole wave shares s (512 % 64 == 0)
    int m = i % H;

    const float4* Wr = (const float4*)(W + (size_t)m * H);   // per-lane stream
    const float4* yr = (const float4*)(yT + (size_t)s * H);  // wave broadcast

    float4 c0 = {0,0,0,0}, c1 = {0,0,0,0}, c2 = {0,0,0,0}, c3 = {0,0,0,0};
    for (int t = 0; t < H / 4; t += 4) {
        float4 w0 = Wr[t+0], w1 = Wr[t+1], w2 = Wr[t+2], w3 = Wr[t+3];
        float4 y0 = yr[t+0], y1 = yr[t+1], y2 = yr[t+2], y3 = yr[t+3];
        c0.x = fmaf(w0.x, y0.x, c0.x); c0.y = fmaf(w0.y, y0.y, c0.y);
        c0.z = fmaf(w0.z, y0.z, c0.z); c0.w = fmaf(w0.w, y0.w, c0.w);
        c1.x = fmaf(w1.x, y1.x, c1.x); c1.y = fmaf(w1.y, y1.y, c1.y);
        c1.z = fmaf(w1.z, y1.z, c1.z); c1.w = fmaf(w1.w, y1.w, c1.w);
        c2.x = fmaf(w2.x, y2.x, c2.x); c2.y = fmaf(w2.y, y2.y, c2.y);
        c2.z = fmaf(w2.z, y2.z, c2.z); c2.w = fmaf(w2.w, y2.w, c2.w);
        c3.x = fmaf(w3.x, y3.x, c3.x); c3.y = fmaf(w3.y, y3.y, c3.y);
        c3.z = fmaf(w3.z, y3.z, c3.z); c3.w = fmaf(w3.w, y3.w, c3.w);
    }
    float4 c;
    c.x = c0.x + c1.x + c2.x + c3.x;
    c.y = c0.y + c1.y + c2.y + c3.y;
    c.z = c0.z + c1.z + c2.z + c3.z;
    c.w = c0.w + c1.w + c2.w + c3.w;
    out[i] = (c.x + c.y) + (c.z + c.w);
}

// ---------------------------------------------------------------------------
// Attention, one block (64 threads) per (row a, head slot).
//   sm[b] = kT[a] . qT[b]   (contiguous 512-dots)
//   p     = softmax(sm)
//   att[a*H+hh] = sum_b p[b] * vT[b*H+hh]   (coalesced over hh)
// a = blockIdx.x + a_offset  (layer 3 launches only a=64)
// ---------------------------------------------------------------------------
__global__ void attn_kernel(const float* __restrict__ kT,
                            const float* __restrict__ qT,
                            const float* __restrict__ vT,
                            float* __restrict__ att, int a_offset) {
    int a = blockIdx.x + a_offset;
    int slot = blockIdx.y;
    int tid = threadIdx.x;   // 64

    const float* kk = kT + (size_t)slot * HS;
    const float* qq = qT + (size_t)slot * HS;
    const float* vv = vT + (size_t)slot * HS;
    float* ao = att + (size_t)slot * S * H;

    __shared__ float sm[S];
    __shared__ float p[S];

    const float4* ka = (const float4*)(kk + (size_t)a * H);   // broadcast
    for (int b = tid; b < S; b += 64) {
        const float4* qb = (const float4*)(qq + (size_t)b * H);
        float4 c0 = {0,0,0,0}, c1 = {0,0,0,0}, c2 = {0,0,0,0}, c3 = {0,0,0,0};
        for (int t = 0; t < H / 4; t += 4) {
            float4 k0 = ka[t+0], k1 = ka[t+1], k2 = ka[t+2], k3 = ka[t+3];
            float4 q0 = qb[t+0], q1 = qb[t+1], q2 = qb[t+2], q3 = qb[t+3];
            c0.x = fmaf(k0.x, q0.x, c0.x); c0.y = fmaf(k0.y, q0.y, c0.y);
            c0.z = fmaf(k0.z, q0.z, c0.z); c0.w = fmaf(k0.w, q0.w, c0.w);
            c1.x = fmaf(k1.x, q1.x, c1.x); c1.y = fmaf(k1.y, q1.y, c1.y);
            c1.z = fmaf(k1.z, q1.z, c1.z); c1.w = fmaf(k1.w, q1.w, c1.w);
            c2.x = fmaf(k2.x, q2.x, c2.x); c2.y = fmaf(k2.y, q2.y, c2.y);
            c2.z = fmaf(k2.z, q2.z, c2.z); c2.w = fmaf(k2.w, q2.w, c2.w);
            c3.x = fmaf(k3.x, q3.x, c3.x); c3.y = fmaf(k3.y, q3.y, c3.y);
            c3.z = fmaf(k3.z, q3.z, c3.z); c3.w = fmaf(k3.w, q3.w, c3.w);
        }
        sm[b] = ((c0.x + c0.y) + (c0.z + c0.w)) + ((c1.x + c1.y) + (c1.z + c1.w))
              + ((c2.x + c2.y) + (c2.z + c2.w)) + ((c3.x + c3.y) + (c3.z + c3.w));
    }
    __syncthreads();

    float maxv = -INFINITY;
    for (int i = 0; i < S; ++i) maxv = fmaxf(maxv, sm[i]);
    float sum = 0.0f;
    for (int i = 0; i < S; ++i) sum += expf(sm[i] - maxv);
    float inv = 1.0f / sum;
    for (int b = tid; b < S; b += 64) {
        p[b] = expf(sm[b] - maxv) * inv;
    }
    __syncthreads();

    for (int hh = tid; hh < H; hh += 64) {
        float a0 = 0.f, a1 = 0.f, a2 = 0.f, a3 = 0.f;
        for (int b = 0; b < 64; b += 4) {
            a0 = fmaf(p[b + 0], vv[(b + 0) * H + hh], a0);
            a1 = fmaf(p[b + 1], vv[(b + 1) * H + hh], a1);
            a2 = fmaf(p[b + 2], vv[(b + 2) * H + hh], a2);
            a3 = fmaf(p[b + 3], vv[(b + 3) * H + hh], a3);
        }
        a0 = fmaf(p[64], vv[64 * H + hh], a0);
        ao[(size_t)a * H + hh] = (a0 + a1) + (a2 + a3);
    }
}

// ---------------------------------------------------------------------------
// K-split partials of: yT[s*H+h] = relu( sum_j cat[s,j]*lin[j,h] )
// seg in [0,6): att segment seg/2, j-half (seg&1)*256.
// Thread (s,h) with h fastest -> lin reads wave-coalesced, att broadcast.
// ---------------------------------------------------------------------------
__global__ void linear_partial_kernel(const float* __restrict__ attA,
                                      const float* __restrict__ attB,
                                      const float* __restrict__ attC,
                                      const float* __restrict__ lin,
                                      float* __restrict__ part) {
    int seg = blockIdx.y;
    const float* att = (seg < 2) ? attA : (seg < 4 ? attB : attC);
    int i = blockIdx.x * blockDim.x + threadIdx.x;
    if (i >= HS) return;
    int s = i / H;
    int h = i % H;

    const float* row = att + (size_t)s * H + (seg & 1) * 256;  // broadcast
    const float* L = lin + (size_t)(seg * 256) * H + h;        // coalesced

    float a0 = 0.f, a1 = 0.f, a2 = 0.f, a3 = 0.f;
    for (int j = 0; j < 256; j += 4) {
        a0 = fmaf(row[j + 0], L[(size_t)(j + 0) * H], a0);
        a1 = fmaf(row[j + 1], L[(size_t)(j + 1) * H], a1);
        a2 = fmaf(row[j + 2], L[(size_t)(j + 2) * H], a2);
        a3 = fmaf(row[j + 3], L[(size_t)(j + 3) * H], a3);
    }
    part[(size_t)seg * HS + i] = (a0 + a1) + (a2 + a3);
}

__global__ void combine_relu_kernel(const float* __restrict__ part,
                                    float* __restrict__ yT) {
    int i = blockIdx.x * blockDim.x + threadIdx.x;
    if (i >= HS) return;
    float s = part[i] + part[HS + i] + part[2 * HS + i]
            + part[3 * HS + i] + part[4 * HS + i] + part[5 * HS + i];
    yT[i] = fmaxf(s, 0.0f);
}

// ---------------------------------------------------------------------------
// Final stage (unchanged from round 1): att rows are [s][h] so row 64 is
// contiguous in all three inputs.
// ---------------------------------------------------------------------------
__global__ void lin3_partial_kernel(const float* __restrict__ attA,
                                    const float* __restrict__ attB,
                                    const float* __restrict__ attC,
                                    const float* __restrict__ lin3,
                                    float* __restrict__ tpart) {
    int j2 = blockIdx.x * 256 + threadIdx.x;   // [0, 1024)
    int ks = blockIdx.y;                       // [0, 24)
    const float* row = (ks < 8) ? (attA + (size_t)64 * H)
                     : (ks < 16 ? (attB + (size_t)64 * H)
                                : (attC + (size_t)64 * H));
    int j0 = (ks & 7) * 64;
    int jbase = ks * 64;

    float a0 = 0.f, a1 = 0.f, a2 = 0.f, a3 = 0.f;
    for (int j = 0; j < 64; j += 4) {
        a0 = fmaf(row[j0 + j + 0], lin3[(size_t)(jbase + j + 0) * 1024 + j2], a0);
        a1 = fmaf(row[j0 + j + 1], lin3[(size_t)(jbase + j + 1) * 1024 + j2], a1);
        a2 = fmaf(row[j0 + j + 2], lin3[(size_t)(jbase + j + 2) * 1024 + j2], a2);
        a3 = fmaf(row[j0 + j + 3], lin3[(size_t)(jbase + j + 3) * 1024 + j2], a3);
    }
    tpart[ks * 1024 + j2] = (a0 + a1) + (a2 + a3);
}

__global__ void lin4_partial_kernel(const float* __restrict__ tpart,
                                    const float* __restrict__ lin4,
                                    float* __restrict__ upart) {
    __shared__ float tl[64];
    int hh = blockIdx.x * 256 + threadIdx.x;   // [0, 512)
    int ks = blockIdx.y;                       // [0, 16)
    int j2base = ks * 64;

    if (threadIdx.x < 64) {
        int j2 = j2base + threadIdx.x;
        float s = 0.f;
#pragma unroll
        for (int p = 0; p < KS3; ++p) s += tpart[p * 1024 + j2];
        tl[threadIdx.x] = fmaxf(s, 0.f);
    }
    __syncthreads();

    float a0 = 0.f, a1 = 0.f, a2 = 0.f, a3 = 0.f;
    for (int j = 0; j < 64; j += 4) {
        a0 = fmaf(tl[j + 0], lin4[(size_t)(j2base + j + 0) * H + hh], a0);
        a1 = fmaf(tl[j + 1], lin4[(size_t)(j2base + j + 1) * H + hh], a1);
        a2 = fmaf(tl[j + 2], lin4[(size_t)(j2base + j + 2) * H + hh], a2);
        a3 = fmaf(tl[j + 3], lin4[(size_t)(j2base + j + 3) * H + hh], a3);
    }
    upart[ks * H + hh] = (a0 + a1) + (a2 + a3);
}

__global__ void final_out_kernel(const float* __restrict__ upart,
                                 const float* __restrict__ lin5,
                                 float* __restrict__ out) {
    __shared__ float u[H];
    __shared__ float pr[8][64];
    int tid = threadIdx.x;   // 512

    {
        float s = 0.f;
#pragma unroll
        for (int p = 0; p < KS4; ++p) s += upart[p * H + tid];
        u[tid] = tanhf(s);
    }
    __syncthreads();

    int o  = tid & 63;
    int sl = tid >> 6;
    float acc = 0.f;
    int h0 = sl * 64;
#pragma unroll 8
    for (int j = 0; j < 64; ++j) {
        acc = fmaf(u[h0 + j], lin5[(h0 + j) * 64 + o], acc);
    }
    pr[sl][o] = acc;
    __syncthreads();

    if (tid < 64) {
        float s = 0.f;
#pragma unroll
        for (int p = 0; p < 8; ++p) s += pr[p][tid];
        out[tid] = s;
    }
}

// ---------------------------------------------------------------------------
extern "C" void kernel_launch(void* const* d_in, const int* in_sizes, int n_in,
                              void* d_out, int out_size, void* d_ws, size_t ws_size,
                              hipStream_t stream) {
    const float* inputs  = (const float*)d_in[0];
    const float* emb     = (const float*)d_in[1];
    const float* wq      = (const float*)d_in[2];
    const float* wk      = (const float*)d_in[3];
    const float* wv      = (const float*)d_in[4];
    const float* linear1 = (const float*)d_in[5];
    const float* linear2 = (const float*)d_in[6];
    const float* linear3 = (const float*)d_in[7];
    const float* linear4 = (const float*)d_in[8];
    const float* linear5 = (const float*)d_in[9];
    float* out = (float*)d_out;

    float* ws    = (float*)d_ws;
    float* y     = ws;                 // HS
    float* kT    = y     + HS;         // 3*HS
    float* qT    = kT    + 3 * HS;     // 3*HS
    float* vT    = qT    + 3 * HS;     // 3*HS
    float* att1  = vT    + 3 * HS;     // 3*HS
    float* att2  = att1  + 3 * HS;     // HS
    float* att3  = att2  + HS;         // HS
    float* part  = att3  + HS;         // 6*HS
    float* tpart = part  + 6 * HS;     // 24*1024
    float* upart = tpart + KS3 * 1024; // 16*512

    const int nb = HS / 256;           // 130

    scale_embed_kernel<<<nb, 256, 0, stream>>>(inputs, emb, y);

    // ---- Layer 1: all 3 heads ----
    kqv_gemm_kernel<<<dim3(nb, 3, 3), 256, 0, stream>>>(wq, wk, wv, 0, 0, y, kT, qT, vT);
    attn_kernel<<<dim3(S, 3), 64, 0, stream>>>(kT, qT, vT, att1, 0);
    linear_partial_kernel<<<dim3(nb, 6), 256, 0, stream>>>(att1, att1 + HS, att1 + 2 * HS,
                                                           linear1, part);
    combine_relu_kernel<<<nb, 256, 0, stream>>>(part, y);

    // ---- Layer 2: only head 2 is consumed ----
    kqv_gemm_kernel<<<dim3(nb, 3, 1), 256, 0, stream>>>(wq, wk, wv, 1, 2, y, kT, qT, vT);
    attn_kernel<<<dim3(S, 1), 64, 0, stream>>>(kT, qT, vT, att2, 0);
    linear_partial_kernel<<<dim3(nb, 6), 256, 0, stream>>>(att1, att1 + HS, att2,
                                                           linear2, part);
    combine_relu_kernel<<<nb, 256, 0, stream>>>(part, y);

    // ---- Layer 3: only head 2, and only row a=64 of its attention ----
    kqv_gemm_kernel<<<dim3(nb, 3, 1), 256, 0, stream>>>(wq, wk, wv, 2, 2, y, kT, qT, vT);
    attn_kernel<<<dim3(1, 1), 64, 0, stream>>>(kT, qT, vT, att3, 64);

    // ---- Final stage ----
    lin3_partial_kernel<<<dim3(4, KS3), 256, 0, stream>>>(att1, att1 + HS, att3, linear3, tpart);
    lin4_partial_kernel<<<dim3(2, KS4), 256, 0, stream>>>(tpart, linear4, upart);
    final_out_kernel<<<1, 512, 0, stream>>>(upart, linear5, out);
}